// Round 11
// baseline (79.725 us; speedup 1.0000x reference)
//
#include <hip/hip_runtime.h>
#include <hip/hip_bf16.h>
#include <math.h>

#define BB 64
#define TT 512
#define CC 384
#define HH 64
#define MM (BB*TT)   // 32768 rows

// 0.125 (H^-0.5) * log2(e): scores hit hw exp2 directly; exp2(s*0.125*log2e)==exp(s*0.125)
#define QSCALE 0.18033688011112042f

typedef __attribute__((ext_vector_type(8))) short short8;
typedef __attribute__((ext_vector_type(4))) float f32x4;

__device__ __forceinline__ unsigned short f2bf(float f) {
    union { float f; unsigned int u; } x; x.f = f;
    unsigned int r = x.u + 0x7fff + ((x.u >> 16) & 1);   // RNE
    return (unsigned short)(r >> 16);
}

// native conversion: compiler emits v_cvt
__device__ __forceinline__ unsigned short bfc(float f) {
    __hip_bfloat16 h = __float2bfloat16(f);
    return *reinterpret_cast<unsigned short*>(&h);
}

// ---------------- Kernel 0: W transpose + bf16 convert (unchanged) ----------------
__global__ __launch_bounds__(256) void prep_w(
    const float* __restrict__ Wq, const float* __restrict__ Wk,
    const float* __restrict__ Wv, unsigned short* __restrict__ Wt)
{
    __shared__ float t[64][65];
    const int which = blockIdx.x / 6;
    const int kt    = blockIdx.x % 6;
    const float* W = (which == 0) ? Wq : (which == 1) ? Wk : Wv;
    const float sc = (which == 0) ? QSCALE : 1.f;
    const int tid = threadIdx.x;
    #pragma unroll
    for (int i = 0; i < 16; i++) {
        int idx = tid + i * 256;
        int kl = idx >> 6, n = idx & 63;
        t[kl][n] = W[(size_t)(kt * 64 + kl) * HH + n];
    }
    __syncthreads();
    #pragma unroll
    for (int i = 0; i < 16; i++) {
        int idx = tid + i * 256;
        int nl = idx >> 6, kl = idx & 63;
        Wt[(size_t)(which * 64 + nl) * CC + kt * 64 + kl] = f2bf(t[kl][nl] * sc);
    }
}

// ---------------- Kernel 1: QKV projection -- 8x REP PROBE + all-packed epilogue ----
// PROBE: {B-prefetch + stage + 3-chunk double-buffered compute} repeated 8x,
// acc accumulated across reps (no re-zero; carried fp32 dependency prevents
// collapse; barriers pin the loads). Epilogue divides by 8 (exact, pow2).
// NEW epilogue: v ALSO goes through the LDS transpose tile (192 rows) ->
// vt stores are contiguous 16B along t. NO scattered stores anywhere.
__global__ __launch_bounds__(256) void qkv_proj_mfma(
    const float* __restrict__ x, const unsigned short* __restrict__ Wt,
    const float* __restrict__ bq, const float* __restrict__ bk,
    const float* __restrict__ bv,
    unsigned short* __restrict__ qb, unsigned short* __restrict__ kb,
    unsigned short* __restrict__ vt)
{
    __shared__ unsigned short lds[2 * 64 * 136];   // 34,816 B (xbuf; L aliases 27,648 B)
#define XB(buf, r, c) lds[(buf) * 8704 + (r) * 136 + (c)]
    const int tid  = threadIdx.x;
    const int w    = tid >> 6;
    const int lane = tid & 63;
    const int l15  = lane & 15;
    const int lg   = lane >> 4;
    const int rows0 = blockIdx.x * 64;
    const int sr   = tid >> 2;          // stage row 0..63
    const int sc0  = (tid & 3) * 32;    // stage col group

    f32x4 acc[4][3];
    #pragma unroll
    for (int mi = 0; mi < 4; mi++)
        #pragma unroll
        for (int f = 0; f < 3; f++) acc[mi][f] = (f32x4){0.f, 0.f, 0.f, 0.f};

    #pragma unroll 1
    for (int rep = 0; rep < 8; ++rep) {
        // B prefetch pipeline (register, from L2-hot Wt)
        short8 bcur[3], bnxt[3];
        #pragma unroll
        for (int f = 0; f < 3; f++)
            bcur[f] = *reinterpret_cast<const short8*>(
                &Wt[(size_t)(w * 48 + f * 16 + l15) * CC + lg * 8]);

        // prologue: stage chunk 0
        {
            float4 ld[8];
            #pragma unroll
            for (int u = 0; u < 8; u++)
                ld[u] = *reinterpret_cast<const float4*>(
                    &x[(size_t)(rows0 + sr) * CC + sc0 + u * 4]);
            #pragma unroll
            for (int u = 0; u < 4; u++) {
                short8 pk;
                pk[0] = bfc(ld[2*u].x);   pk[1] = bfc(ld[2*u].y);
                pk[2] = bfc(ld[2*u].z);   pk[3] = bfc(ld[2*u].w);
                pk[4] = bfc(ld[2*u+1].x); pk[5] = bfc(ld[2*u+1].y);
                pk[6] = bfc(ld[2*u+1].z); pk[7] = bfc(ld[2*u+1].w);
                *reinterpret_cast<short8*>(&XB(0, sr, sc0 + u * 8)) = pk;
            }
        }
        __syncthreads();

        #pragma unroll
        for (int c = 0; c < 3; ++c) {
            float4 ldn[8];
            if (c < 2) {
                #pragma unroll
                for (int u = 0; u < 8; u++)
                    ldn[u] = *reinterpret_cast<const float4*>(
                        &x[(size_t)(rows0 + sr) * CC + (c + 1) * 128 + sc0 + u * 4]);
            }

            #pragma unroll
            for (int kk = 0; kk < 4; ++kk) {
                const int kg = c * 4 + kk;
                if (kg < 11) {
                    #pragma unroll
                    for (int f = 0; f < 3; f++)
                        bnxt[f] = *reinterpret_cast<const short8*>(
                            &Wt[(size_t)(w * 48 + f * 16 + l15) * CC + (kg + 1) * 32 + lg * 8]);
                }
                short8 afrag[4];
                #pragma unroll
                for (int mi = 0; mi < 4; mi++)
                    afrag[mi] = *reinterpret_cast<const short8*>(
                        &XB(c & 1, mi * 16 + l15, kk * 32 + lg * 8));
                #pragma unroll
                for (int f = 0; f < 3; f++)
                    #pragma unroll
                    for (int mi = 0; mi < 4; mi++)
                        acc[mi][f] = __builtin_amdgcn_mfma_f32_16x16x32_bf16(
                            afrag[mi], bcur[f], acc[mi][f], 0, 0, 0);
                #pragma unroll
                for (int f = 0; f < 3; f++) bcur[f] = bnxt[f];
            }

            if (c < 2) {
                #pragma unroll
                for (int u = 0; u < 4; u++) {
                    short8 pk;
                    pk[0] = bfc(ldn[2*u].x);   pk[1] = bfc(ldn[2*u].y);
                    pk[2] = bfc(ldn[2*u].z);   pk[3] = bfc(ldn[2*u].w);
                    pk[4] = bfc(ldn[2*u+1].x); pk[5] = bfc(ldn[2*u+1].y);
                    pk[6] = bfc(ldn[2*u+1].z); pk[7] = bfc(ldn[2*u+1].w);
                    *reinterpret_cast<short8*>(&XB((c + 1) & 1, sr, sc0 + u * 8)) = pk;
                }
            }
            __syncthreads();
        }
    }

    // ---- epilogue (once). acc holds 8x result -> scale 0.125 (exact pow2).
    // D: col = lane&15, row = (lane>>4)*4 + reg.
    const int batch = rows0 >> 9;
    const int t0    = rows0 & 511;

    unsigned short (*L)[72] = reinterpret_cast<unsigned short (*)[72]>(&lds[0]);
    // L rows 0..63 = q [t][c], 64..127 = k [t][c], 128..191 = v TRANSPOSED [ci][t]

    #pragma unroll
    for (int f = 0; f < 3; f++) {
        const int c = w * 48 + f * 16 + l15;   // 0..191, disjoint per wave
        if (c < 64) {
            const float bb = bq[c] * QSCALE;
            #pragma unroll
            for (int mi = 0; mi < 4; mi++)
                #pragma unroll
                for (int rr = 0; rr < 4; rr++)
                    L[mi * 16 + lg * 4 + rr][c] = f2bf(acc[mi][f][rr] * 0.125f + bb);
        } else if (c < 128) {
            const int ci = c - 64;
            const float bb = bk[ci];
            #pragma unroll
            for (int mi = 0; mi < 4; mi++)
                #pragma unroll
                for (int rr = 0; rr < 4; rr++)
                    L[64 + mi * 16 + lg * 4 + rr][ci] = f2bf(acc[mi][f][rr] * 0.125f + bb);
        } else {
            const int ci = c - 128;
            const float bb = bv[ci];
            #pragma unroll
            for (int mi = 0; mi < 4; mi++)
                #pragma unroll
                for (int rr = 0; rr < 4; rr++)
                    L[128 + ci][mi * 16 + lg * 4 + rr] = f2bf(acc[mi][f][rr] * 0.125f + bb);
        }
    }
    __syncthreads();

    // cooperative packed store: 192 rows x 8 x 16B, ALL contiguous
    #pragma unroll
    for (int i = 0; i < 6; i++) {
        int idx = tid + i * 256;          // 0..1535
        int r = idx >> 3, c8 = idx & 7;
        const short8 val = *reinterpret_cast<const short8*>(&L[r][c8 * 8]);
        if (r < 64)
            *reinterpret_cast<short8*>(&qb[(size_t)(rows0 + r) * HH + c8 * 8]) = val;
        else if (r < 128)
            *reinterpret_cast<short8*>(&kb[(size_t)(rows0 + r - 64) * HH + c8 * 8]) = val;
        else
            *reinterpret_cast<short8*>(
                &vt[((size_t)batch * HH + (r - 128)) * TT + t0 + c8 * 8]) = val;
    }
#undef XB
}

// ---------------- Kernel 2: MFMA flash attention, 4-way split-K (round-6, frozen) ----------------
__global__ __launch_bounds__(256, 3) void attn_mfma(
    const unsigned short* __restrict__ q, const unsigned short* __restrict__ k,
    const unsigned short* __restrict__ vt, float* __restrict__ out)
{
    __shared__ float Cmb[4][16][68];
    __shared__ float Ls[4][16];
    __shared__ unsigned short P[4][16][72];
    const int tid  = threadIdx.x;
    const int w    = tid >> 6;
    const int lane = tid & 63;
    const int l15  = lane & 15;
    const int lg   = lane >> 4;
    const int qs   = blockIdx.x >> 6;       // 0..31
    const int b    = blockIdx.x & 63;
    const int qr0  = b * TT + qs * 16;
    const int n    = (qs >> 2) + 1;

    const unsigned short* __restrict__ kbase = k  + (size_t)b * TT * HH;
    const unsigned short* __restrict__ vbase = vt + (size_t)b * HH * TT;

    short8 aq[2];
    #pragma unroll
    for (int ks = 0; ks < 2; ks++)
        aq[ks] = *reinterpret_cast<const short8*>(
            &q[(size_t)(qr0 + l15) * HH + ks * 32 + lg * 8]);

    f32x4 accO[4];
    #pragma unroll
    for (int nf = 0; nf < 4; nf++) accO[nf] = (f32x4){0.f, 0.f, 0.f, 0.f};
    float lsum[4] = {0.f, 0.f, 0.f, 0.f};

    for (int j = w; j < n; j += 4) {
        short8 kf[2][4];
        #pragma unroll
        for (int ks = 0; ks < 2; ks++)
            #pragma unroll
            for (int nf = 0; nf < 4; nf++)
                kf[ks][nf] = *reinterpret_cast<const short8*>(
                    &kbase[(size_t)(j * 64 + nf * 16 + l15) * HH + ks * 32 + lg * 8]);
        f32x4 s[4];
        #pragma unroll
        for (int nf = 0; nf < 4; nf++) s[nf] = (f32x4){0.f, 0.f, 0.f, 0.f};
        #pragma unroll
        for (int ks = 0; ks < 2; ks++)
            #pragma unroll
            for (int nf = 0; nf < 4; nf++)
                s[nf] = __builtin_amdgcn_mfma_f32_16x16x32_bf16(
                    aq[ks], kf[ks][nf], s[nf], 0, 0, 0);

        short8 vf[2][4];
        #pragma unroll
        for (int ks = 0; ks < 2; ks++)
            #pragma unroll
            for (int nf = 0; nf < 4; nf++)
                vf[ks][nf] = *reinterpret_cast<const short8*>(
                    &vbase[(size_t)(nf * 16 + l15) * TT + j * 64 + ks * 32 + lg * 8]);

        float p[4][4];
        if (j == n - 1) {
            #pragma unroll
            for (int nf = 0; nf < 4; nf++)
                #pragma unroll
                for (int rg = 0; rg < 4; rg++)
                    p[nf][rg] = (j * 64 + nf * 16 + l15 > qs * 16 + lg * 4 + rg)
                                ? 0.f : exp2f(s[nf][rg]);
        } else {
            #pragma unroll
            for (int nf = 0; nf < 4; nf++)
                #pragma unroll
                for (int rg = 0; rg < 4; rg++)
                    p[nf][rg] = exp2f(s[nf][rg]);
        }
        #pragma unroll
        for (int rg = 0; rg < 4; rg++)
            lsum[rg] += (p[0][rg] + p[1][rg]) + (p[2][rg] + p[3][rg]);

        #pragma unroll
        for (int nf = 0; nf < 4; nf++)
            #pragma unroll
            for (int rg = 0; rg < 4; rg++)
                P[w][lg * 4 + rg][nf * 16 + l15] = f2bf(p[nf][rg]);

        #pragma unroll
        for (int ks = 0; ks < 2; ks++) {
            const short8 pa = *reinterpret_cast<const short8*>(
                &P[w][l15][ks * 32 + lg * 8]);
            #pragma unroll
            for (int nf = 0; nf < 4; nf++)
                accO[nf] = __builtin_amdgcn_mfma_f32_16x16x32_bf16(
                    pa, vf[ks][nf], accO[nf], 0, 0, 0);
        }
    }

    #pragma unroll
    for (int rg = 0; rg < 4; rg++) {
        float l = lsum[rg];
        l += __shfl_xor(l, 1);
        l += __shfl_xor(l, 2);
        l += __shfl_xor(l, 4);
        l += __shfl_xor(l, 8);
        if (l15 == 0) Ls[w][lg * 4 + rg] = l;
    }
    #pragma unroll
    for (int nf = 0; nf < 4; nf++)
        #pragma unroll
        for (int rg = 0; rg < 4; rg++)
            Cmb[w][lg * 4 + rg][nf * 16 + l15] = accO[nf][rg];
    __syncthreads();

    #pragma unroll
    for (int rg = 0; rg < 4; rg++) {
        const int row = lg * 4 + rg;
        const float ltot = Ls[0][row] + Ls[1][row] + Ls[2][row] + Ls[3][row];
        const float sum = Cmb[0][row][w * 16 + l15] + Cmb[1][row][w * 16 + l15]
                        + Cmb[2][row][w * 16 + l15] + Cmb[3][row][w * 16 + l15];
        out[(size_t)(qr0 + row) * HH + w * 16 + l15] = sum / ltot;
    }
}

extern "C" void kernel_launch(void* const* d_in, const int* in_sizes, int n_in,
                              void* d_out, int out_size, void* d_ws, size_t ws_size,
                              hipStream_t stream) {
    const float* x  = (const float*)d_in[0];
    const float* Wq = (const float*)d_in[1];
    const float* bq = (const float*)d_in[2];
    const float* Wk = (const float*)d_in[3];
    const float* bk = (const float*)d_in[4];
    const float* Wv = (const float*)d_in[5];
    const float* bv = (const float*)d_in[6];
    float* out = (float*)d_out;

    unsigned short* qb = (unsigned short*)d_ws;        // [M][64] bf16 (pre-scaled)
    unsigned short* kb = qb + (size_t)MM * HH;         // [M][64] bf16
    unsigned short* vt = kb + (size_t)MM * HH;         // [B][64][512] bf16
    unsigned short* Wt = vt + (size_t)MM * HH;         // [192][384] bf16

    prep_w<<<dim3(18), dim3(256), 0, stream>>>(Wq, Wk, Wv, Wt);
    qkv_proj_mfma<<<dim3(MM / 64), dim3(256), 0, stream>>>(
        x, Wt, bq, bk, bv, qb, kb, vt);
    attn_mfma<<<dim3(2048), dim3(256), 0, stream>>>(qb, kb, vt, out);
}

// Round 12
// 51.867 us; speedup vs baseline: 1.5371x; 1.5371x over previous
//
#include <hip/hip_runtime.h>
#include <hip/hip_bf16.h>
#include <math.h>

#define BB 64
#define TT 512
#define CC 384
#define HH 64
#define MM (BB*TT)   // 32768 rows

// 0.125 (H^-0.5) * log2(e): scores hit hw exp2 directly; exp2(s*0.125*log2e)==exp(s*0.125)
#define QSCALE 0.18033688011112042f

typedef __attribute__((ext_vector_type(8))) short short8;
typedef __attribute__((ext_vector_type(4))) float f32x4;

__device__ __forceinline__ unsigned short f2bf(float f) {
    union { float f; unsigned int u; } x; x.f = f;
    unsigned int r = x.u + 0x7fff + ((x.u >> 16) & 1);   // RNE
    return (unsigned short)(r >> 16);
}

// native conversion: compiler emits v_cvt
__device__ __forceinline__ unsigned short bfc(float f) {
    __hip_bfloat16 h = __float2bfloat16(f);
    return *reinterpret_cast<unsigned short*>(&h);
}

// ---------------- Kernel 0: W transpose + bf16 convert (unchanged) ----------------
__global__ __launch_bounds__(256) void prep_w(
    const float* __restrict__ Wq, const float* __restrict__ Wk,
    const float* __restrict__ Wv, unsigned short* __restrict__ Wt)
{
    __shared__ float t[64][65];
    const int which = blockIdx.x / 6;
    const int kt    = blockIdx.x % 6;
    const float* W = (which == 0) ? Wq : (which == 1) ? Wk : Wv;
    const float sc = (which == 0) ? QSCALE : 1.f;
    const int tid = threadIdx.x;
    #pragma unroll
    for (int i = 0; i < 16; i++) {
        int idx = tid + i * 256;
        int kl = idx >> 6, n = idx & 63;
        t[kl][n] = W[(size_t)(kt * 64 + kl) * HH + n];
    }
    __syncthreads();
    #pragma unroll
    for (int i = 0; i < 16; i++) {
        int idx = tid + i * 256;
        int nl = idx >> 6, kl = idx & 63;
        Wt[(size_t)(which * 64 + nl) * CC + kt * 64 + kl] = f2bf(t[kl][nl] * sc);
    }
}

// ---------------- Kernel 1: QKV projection, single-pass + ALL-PACKED epilogue ----
// r11 probe isolated the sink: the loop {stage + 3-chunk dbuf compute} is only
// ~7us warm; the old scattered-vt ushort4 stores (64 lanes x 8B @ 1KB stride)
// cost ~21us. This is the r11 kernel with rep=1: v joins q/k in the LDS
// transpose tile (192 rows) so EVERY global store is a contiguous 16B b128.
__global__ __launch_bounds__(256) void qkv_proj_mfma(
    const float* __restrict__ x, const unsigned short* __restrict__ Wt,
    const float* __restrict__ bq, const float* __restrict__ bk,
    const float* __restrict__ bv,
    unsigned short* __restrict__ qb, unsigned short* __restrict__ kb,
    unsigned short* __restrict__ vt)
{
    __shared__ unsigned short lds[2 * 64 * 136];   // 34,816 B (xbuf; L aliases 27,648 B)
#define XB(buf, r, c) lds[(buf) * 8704 + (r) * 136 + (c)]
    const int tid  = threadIdx.x;
    const int w    = tid >> 6;
    const int lane = tid & 63;
    const int l15  = lane & 15;
    const int lg   = lane >> 4;
    const int rows0 = blockIdx.x * 64;
    const int sr   = tid >> 2;          // stage row 0..63
    const int sc0  = (tid & 3) * 32;    // stage col group

    f32x4 acc[4][3];
    #pragma unroll
    for (int mi = 0; mi < 4; mi++)
        #pragma unroll
        for (int f = 0; f < 3; f++) acc[mi][f] = (f32x4){0.f, 0.f, 0.f, 0.f};

    // B prefetch pipeline (register, from L2-hot Wt)
    short8 bcur[3], bnxt[3];
    #pragma unroll
    for (int f = 0; f < 3; f++)
        bcur[f] = *reinterpret_cast<const short8*>(
            &Wt[(size_t)(w * 48 + f * 16 + l15) * CC + lg * 8]);

    // prologue: stage chunk 0
    {
        float4 ld[8];
        #pragma unroll
        for (int u = 0; u < 8; u++)
            ld[u] = *reinterpret_cast<const float4*>(
                &x[(size_t)(rows0 + sr) * CC + sc0 + u * 4]);
        #pragma unroll
        for (int u = 0; u < 4; u++) {
            short8 pk;
            pk[0] = bfc(ld[2*u].x);   pk[1] = bfc(ld[2*u].y);
            pk[2] = bfc(ld[2*u].z);   pk[3] = bfc(ld[2*u].w);
            pk[4] = bfc(ld[2*u+1].x); pk[5] = bfc(ld[2*u+1].y);
            pk[6] = bfc(ld[2*u+1].z); pk[7] = bfc(ld[2*u+1].w);
            *reinterpret_cast<short8*>(&XB(0, sr, sc0 + u * 8)) = pk;
        }
    }
    __syncthreads();

    #pragma unroll
    for (int c = 0; c < 3; ++c) {
        // issue next chunk's loads EARLY (fly under this chunk's compute)
        float4 ldn[8];
        if (c < 2) {
            #pragma unroll
            for (int u = 0; u < 8; u++)
                ldn[u] = *reinterpret_cast<const float4*>(
                    &x[(size_t)(rows0 + sr) * CC + (c + 1) * 128 + sc0 + u * 4]);
        }

        // compute chunk c from xbuf[c&1]; B register-prefetched one ks ahead
        #pragma unroll
        for (int kk = 0; kk < 4; ++kk) {
            const int kg = c * 4 + kk;
            if (kg < 11) {
                #pragma unroll
                for (int f = 0; f < 3; f++)
                    bnxt[f] = *reinterpret_cast<const short8*>(
                        &Wt[(size_t)(w * 48 + f * 16 + l15) * CC + (kg + 1) * 32 + lg * 8]);
            }
            short8 afrag[4];
            #pragma unroll
            for (int mi = 0; mi < 4; mi++)
                afrag[mi] = *reinterpret_cast<const short8*>(
                    &XB(c & 1, mi * 16 + l15, kk * 32 + lg * 8));
            #pragma unroll
            for (int f = 0; f < 3; f++)
                #pragma unroll
                for (int mi = 0; mi < 4; mi++)
                    acc[mi][f] = __builtin_amdgcn_mfma_f32_16x16x32_bf16(
                        afrag[mi], bcur[f], acc[mi][f], 0, 0, 0);
            #pragma unroll
            for (int f = 0; f < 3; f++) bcur[f] = bnxt[f];
        }

        // write-late: loads have landed under compute; cvt + ds_write
        if (c < 2) {
            #pragma unroll
            for (int u = 0; u < 4; u++) {
                short8 pk;
                pk[0] = bfc(ldn[2*u].x);   pk[1] = bfc(ldn[2*u].y);
                pk[2] = bfc(ldn[2*u].z);   pk[3] = bfc(ldn[2*u].w);
                pk[4] = bfc(ldn[2*u+1].x); pk[5] = bfc(ldn[2*u+1].y);
                pk[6] = bfc(ldn[2*u+1].z); pk[7] = bfc(ldn[2*u+1].w);
                *reinterpret_cast<short8*>(&XB((c + 1) & 1, sr, sc0 + u * 8)) = pk;
            }
        }
        __syncthreads();
    }

    // ---- epilogue. D: col = lane&15, row = (lane>>4)*4 + reg ----
    const int batch = rows0 >> 9;
    const int t0    = rows0 & 511;

    unsigned short (*L)[72] = reinterpret_cast<unsigned short (*)[72]>(&lds[0]);
    // L rows 0..63 = q [t][c], 64..127 = k [t][c], 128..191 = v TRANSPOSED [ci][t]

    #pragma unroll
    for (int f = 0; f < 3; f++) {
        const int c = w * 48 + f * 16 + l15;   // 0..191, disjoint per wave
        if (c < 64) {
            const float bb = bq[c] * QSCALE;
            #pragma unroll
            for (int mi = 0; mi < 4; mi++)
                #pragma unroll
                for (int rr = 0; rr < 4; rr++)
                    L[mi * 16 + lg * 4 + rr][c] = f2bf(acc[mi][f][rr] + bb);
        } else if (c < 128) {
            const int ci = c - 64;
            const float bb = bk[ci];
            #pragma unroll
            for (int mi = 0; mi < 4; mi++)
                #pragma unroll
                for (int rr = 0; rr < 4; rr++)
                    L[64 + mi * 16 + lg * 4 + rr][ci] = f2bf(acc[mi][f][rr] + bb);
        } else {
            const int ci = c - 128;
            const float bb = bv[ci];
            #pragma unroll
            for (int mi = 0; mi < 4; mi++)
                #pragma unroll
                for (int rr = 0; rr < 4; rr++)
                    L[128 + ci][mi * 16 + lg * 4 + rr] = f2bf(acc[mi][f][rr] + bb);
        }
    }
    __syncthreads();

    // cooperative packed store: 192 rows x 8 x 16B, ALL contiguous
    #pragma unroll
    for (int i = 0; i < 6; i++) {
        int idx = tid + i * 256;          // 0..1535
        int r = idx >> 3, c8 = idx & 7;
        const short8 val = *reinterpret_cast<const short8*>(&L[r][c8 * 8]);
        if (r < 64)
            *reinterpret_cast<short8*>(&qb[(size_t)(rows0 + r) * HH + c8 * 8]) = val;
        else if (r < 128)
            *reinterpret_cast<short8*>(&kb[(size_t)(rows0 + r - 64) * HH + c8 * 8]) = val;
        else
            *reinterpret_cast<short8*>(
                &vt[((size_t)batch * HH + (r - 128)) * TT + t0 + c8 * 8]) = val;
    }
#undef XB
}

// ---------------- Kernel 2: MFMA flash attention, 4-way split-K (round-6, frozen) ----------------
__global__ __launch_bounds__(256, 3) void attn_mfma(
    const unsigned short* __restrict__ q, const unsigned short* __restrict__ k,
    const unsigned short* __restrict__ vt, float* __restrict__ out)
{
    __shared__ float Cmb[4][16][68];
    __shared__ float Ls[4][16];
    __shared__ unsigned short P[4][16][72];
    const int tid  = threadIdx.x;
    const int w    = tid >> 6;
    const int lane = tid & 63;
    const int l15  = lane & 15;
    const int lg   = lane >> 4;
    const int qs   = blockIdx.x >> 6;       // 0..31
    const int b    = blockIdx.x & 63;
    const int qr0  = b * TT + qs * 16;
    const int n    = (qs >> 2) + 1;

    const unsigned short* __restrict__ kbase = k  + (size_t)b * TT * HH;
    const unsigned short* __restrict__ vbase = vt + (size_t)b * HH * TT;

    short8 aq[2];
    #pragma unroll
    for (int ks = 0; ks < 2; ks++)
        aq[ks] = *reinterpret_cast<const short8*>(
            &q[(size_t)(qr0 + l15) * HH + ks * 32 + lg * 8]);

    f32x4 accO[4];
    #pragma unroll
    for (int nf = 0; nf < 4; nf++) accO[nf] = (f32x4){0.f, 0.f, 0.f, 0.f};
    float lsum[4] = {0.f, 0.f, 0.f, 0.f};

    for (int j = w; j < n; j += 4) {
        short8 kf[2][4];
        #pragma unroll
        for (int ks = 0; ks < 2; ks++)
            #pragma unroll
            for (int nf = 0; nf < 4; nf++)
                kf[ks][nf] = *reinterpret_cast<const short8*>(
                    &kbase[(size_t)(j * 64 + nf * 16 + l15) * HH + ks * 32 + lg * 8]);
        f32x4 s[4];
        #pragma unroll
        for (int nf = 0; nf < 4; nf++) s[nf] = (f32x4){0.f, 0.f, 0.f, 0.f};
        #pragma unroll
        for (int ks = 0; ks < 2; ks++)
            #pragma unroll
            for (int nf = 0; nf < 4; nf++)
                s[nf] = __builtin_amdgcn_mfma_f32_16x16x32_bf16(
                    aq[ks], kf[ks][nf], s[nf], 0, 0, 0);

        short8 vf[2][4];
        #pragma unroll
        for (int ks = 0; ks < 2; ks++)
            #pragma unroll
            for (int nf = 0; nf < 4; nf++)
                vf[ks][nf] = *reinterpret_cast<const short8*>(
                    &vbase[(size_t)(nf * 16 + l15) * TT + j * 64 + ks * 32 + lg * 8]);

        float p[4][4];
        if (j == n - 1) {
            #pragma unroll
            for (int nf = 0; nf < 4; nf++)
                #pragma unroll
                for (int rg = 0; rg < 4; rg++)
                    p[nf][rg] = (j * 64 + nf * 16 + l15 > qs * 16 + lg * 4 + rg)
                                ? 0.f : exp2f(s[nf][rg]);
        } else {
            #pragma unroll
            for (int nf = 0; nf < 4; nf++)
                #pragma unroll
                for (int rg = 0; rg < 4; rg++)
                    p[nf][rg] = exp2f(s[nf][rg]);
        }
        #pragma unroll
        for (int rg = 0; rg < 4; rg++)
            lsum[rg] += (p[0][rg] + p[1][rg]) + (p[2][rg] + p[3][rg]);

        #pragma unroll
        for (int nf = 0; nf < 4; nf++)
            #pragma unroll
            for (int rg = 0; rg < 4; rg++)
                P[w][lg * 4 + rg][nf * 16 + l15] = f2bf(p[nf][rg]);

        #pragma unroll
        for (int ks = 0; ks < 2; ks++) {
            const short8 pa = *reinterpret_cast<const short8*>(
                &P[w][l15][ks * 32 + lg * 8]);
            #pragma unroll
            for (int nf = 0; nf < 4; nf++)
                accO[nf] = __builtin_amdgcn_mfma_f32_16x16x32_bf16(
                    pa, vf[ks][nf], accO[nf], 0, 0, 0);
        }
    }

    #pragma unroll
    for (int rg = 0; rg < 4; rg++) {
        float l = lsum[rg];
        l += __shfl_xor(l, 1);
        l += __shfl_xor(l, 2);
        l += __shfl_xor(l, 4);
        l += __shfl_xor(l, 8);
        if (l15 == 0) Ls[w][lg * 4 + rg] = l;
    }
    #pragma unroll
    for (int nf = 0; nf < 4; nf++)
        #pragma unroll
        for (int rg = 0; rg < 4; rg++)
            Cmb[w][lg * 4 + rg][nf * 16 + l15] = accO[nf][rg];
    __syncthreads();

    #pragma unroll
    for (int rg = 0; rg < 4; rg++) {
        const int row = lg * 4 + rg;
        const float ltot = Ls[0][row] + Ls[1][row] + Ls[2][row] + Ls[3][row];
        const float sum = Cmb[0][row][w * 16 + l15] + Cmb[1][row][w * 16 + l15]
                        + Cmb[2][row][w * 16 + l15] + Cmb[3][row][w * 16 + l15];
        out[(size_t)(qr0 + row) * HH + w * 16 + l15] = sum / ltot;
    }
}

extern "C" void kernel_launch(void* const* d_in, const int* in_sizes, int n_in,
                              void* d_out, int out_size, void* d_ws, size_t ws_size,
                              hipStream_t stream) {
    const float* x  = (const float*)d_in[0];
    const float* Wq = (const float*)d_in[1];
    const float* bq = (const float*)d_in[2];
    const float* Wk = (const float*)d_in[3];
    const float* bk = (const float*)d_in[4];
    const float* Wv = (const float*)d_in[5];
    const float* bv = (const float*)d_in[6];
    float* out = (float*)d_out;

    unsigned short* qb = (unsigned short*)d_ws;        // [M][64] bf16 (pre-scaled)
    unsigned short* kb = qb + (size_t)MM * HH;         // [M][64] bf16
    unsigned short* vt = kb + (size_t)MM * HH;         // [B][64][512] bf16
    unsigned short* Wt = vt + (size_t)MM * HH;         // [192][384] bf16

    prep_w<<<dim3(18), dim3(256), 0, stream>>>(Wq, Wk, Wv, Wt);
    qkv_proj_mfma<<<dim3(MM / 64), dim3(256), 0, stream>>>(
        x, Wt, bq, bk, bv, qb, kb, vt);
    attn_mfma<<<dim3(2048), dim3(256), 0, stream>>>(qb, kb, vt, out);
}